// Round 6
// baseline (233.059 us; speedup 1.0000x reference)
//
#include <hip/hip_runtime.h>
#include <math.h>

// out[b, l, d] = x[b, l, d] + pe[l, d]
// pe[l, 0:128]   : interleaved sin/cos of row * freq_m   (m = 0..63)
// pe[l, 128:256] : interleaved sin/cos of col * freq_m
// freq_m = exp(-m * ln(10000)/64),  l = row * w + col,  d_model = 256
//
// Structure: 4 float4s per thread, stride blockDim within a contiguous
// 1024-float4 (16KB) block chunk. Every memory instruction stays perfectly
// coalesced over consecutive addresses; per-thread MLP = 4 independent
// load streams. Since 256 % 64 == 0, all 4 elements share the same channel
// index j -> the w/h loads and the two __expf's are computed once.
// (Round-4 lesson: NO large-stride multi-streams — chunk-local only.)

typedef float f32x4 __attribute__((ext_vector_type(4)));

__global__ __launch_bounds__(256) void pe_add_kernel(
    const float* __restrict__ x,
    const int* __restrict__ hp,
    const int* __restrict__ wp,
    float* __restrict__ out,
    unsigned int n4)   // total number of float4 elements
{
    const unsigned int base = blockIdx.x * 1024u + threadIdx.x;

    // channel-dependent factors: identical for all 4 elements of this thread
    const unsigned int j  = base & 63u;       // float4 index within d (0..63)
    const unsigned int d0 = j << 2;           // starting channel
    const unsigned int m0 = (d0 & 127u) >> 1; // frequency index of first pair
    const float cstep = 0.14391156831212787f; // ln(10000)/64
    const float f0 = __expf(-(float)m0 * cstep);
    const float f1 = __expf(-(float)(m0 + 1u) * cstep);
    const bool rowhalf = (d0 < 128u);

    const unsigned int ww = (unsigned int)(*wp);
    const unsigned int hh = (unsigned int)(*hp);
    const unsigned int L  = hh * ww;
    const bool pow2 = ((ww & (ww - 1u)) | (L & (L - 1u))) == 0u;
    const unsigned int wshift = (unsigned int)__builtin_ctz(ww);

    const f32x4* __restrict__ xp = reinterpret_cast<const f32x4*>(x);
    f32x4* __restrict__       op = reinterpret_cast<f32x4*>(out);

    // issue all 4 loads first (4 outstanding vmem ops per thread)
    unsigned int idx[4];
    f32x4 xv[4];
    #pragma unroll
    for (int k = 0; k < 4; ++k) {
        idx[k] = base + 256u * (unsigned int)k;
        if (idx[k] < n4) xv[k] = xp[idx[k]];
    }

    #pragma unroll
    for (int k = 0; k < 4; ++k) {
        if (idx[k] >= n4) continue;
        const unsigned int t = idx[k] >> 6;   // b * L + l
        unsigned int l, row, col;
        if (pow2) { l = t & (L - 1u); row = l >> wshift; col = l & (ww - 1u); }
        else      { l = t % L;        row = l / ww;      col = l - row * ww; }
        const float pos = (float)(rowhalf ? row : col);

        float s0, c0, s1, c1;
        __sincosf(pos * f0, &s0, &c0);
        __sincosf(pos * f1, &s1, &c1);

        const f32x4 pe = { s0, c0, s1, c1 };
        op[idx[k]] = xv[k] + pe;
    }
}

extern "C" void kernel_launch(void* const* d_in, const int* in_sizes, int n_in,
                              void* d_out, int out_size, void* d_ws, size_t ws_size,
                              hipStream_t stream) {
    const float* x = (const float*)d_in[0];
    const int* hp  = (const int*)d_in[1];
    const int* wp  = (const int*)d_in[2];
    float* out     = (float*)d_out;

    // out_size is in float elements -> float4 count = /4 (verified)
    const unsigned int n4 = (unsigned int)(out_size / 4);
    const unsigned int blocks = (n4 + 1023u) / 1024u;   // 1024 float4s per block
    pe_add_kernel<<<blocks, 256, 0, stream>>>(x, hp, wp, out, n4);
}

// Round 7
// 226.744 us; speedup vs baseline: 1.0278x; 1.0278x over previous
//
#include <hip/hip_runtime.h>
#include <math.h>

// out[b, l, d] = x[b, l, d] + pe[l, d]
// pe[l, 0:128]   : interleaved sin/cos of row * freq_m   (m = 0..63)
// pe[l, 128:256] : interleaved sin/cos of col * freq_m
// freq_m = exp(-m * ln(10000)/64),  l = row * w + col,  d_model = 256
//
// Structure: round-5 verified linear layout (1 float4/thread, full grid) —
// the ONLY change is a nontemporal store for `out` (write-once stream;
// bypass L2/L3 write-allocate, the suspected 53%-of-ceiling limiter seen in
// round 6's counters: 1.68 TB/s write pace vs fills' 6.8 TB/s).
// Loads stay cached: x (134 MB) is L3-resident across bench iterations.

typedef float f32x4 __attribute__((ext_vector_type(4)));

__global__ __launch_bounds__(256) void pe_add_kernel(
    const float* __restrict__ x,
    const int* __restrict__ hp,
    const int* __restrict__ wp,
    float* __restrict__ out,
    unsigned int n4)   // total number of float4 elements
{
    unsigned int idx = blockIdx.x * blockDim.x + threadIdx.x;
    if (idx >= n4) return;

    const unsigned int ww = (unsigned int)(*wp);
    const unsigned int hh = (unsigned int)(*hp);
    const unsigned int L  = hh * ww;

    const unsigned int j = idx & 63u;   // float4 index within the 256-wide d dim
    const unsigned int t = idx >> 6;    // b * L + l

    // wave-uniform pow2 fast path (bench: w=128, L=16384)
    unsigned int l, row, col;
    if (((ww & (ww - 1u)) | (L & (L - 1u))) == 0u) {
        const unsigned int wshift = (unsigned int)__builtin_ctz(ww);
        l   = t & (L - 1u);
        row = l >> wshift;
        col = l & (ww - 1u);
    } else {
        l   = t % L;
        row = l / ww;
        col = l - row * ww;
    }

    const unsigned int d0 = j << 2;           // starting channel (0..252, step 4)
    const unsigned int dd = d0 & 127u;        // offset within the row/col half
    const float pos = (float)((d0 < 128u) ? row : col);

    const unsigned int m0 = dd >> 1;          // frequency index of first pair
    const float cstep = 0.14391156831212787f; // ln(10000)/64
    const float f0 = __expf(-(float)m0 * cstep);
    const float f1 = __expf(-(float)(m0 + 1u) * cstep);

    float s0, c0, s1, c1;
    __sincosf(pos * f0, &s0, &c0);
    __sincosf(pos * f1, &s1, &c1);

    const f32x4 xv = reinterpret_cast<const f32x4*>(x)[idx];
    const f32x4 pe = { s0, c0, s1, c1 };
    const f32x4 ov = xv + pe;
    __builtin_nontemporal_store(ov, reinterpret_cast<f32x4*>(out) + idx);
}

extern "C" void kernel_launch(void* const* d_in, const int* in_sizes, int n_in,
                              void* d_out, int out_size, void* d_ws, size_t ws_size,
                              hipStream_t stream) {
    const float* x = (const float*)d_in[0];
    const int* hp  = (const int*)d_in[1];
    const int* wp  = (const int*)d_in[2];
    float* out     = (float*)d_out;

    // out_size is in float elements -> float4 count = /4 (verified)
    const unsigned int n4 = (unsigned int)(out_size / 4);
    const unsigned int blocks = (n4 + 255u) / 256u;
    pe_add_kernel<<<blocks, 256, 0, stream>>>(x, hp, wp, out, n4);
}